// Round 17
// baseline (433.405 us; speedup 1.0000x reference)
//
#include <hip/hip_runtime.h>
#include <hip/hip_bf16.h>

#define NROWS 8192
#define DIN   4096
#define DOUT  4096
#define KOUT  16
#define NKT   (DIN / 128)   // 32 K-tiles

typedef __attribute__((ext_vector_type(4)))  int  int4v;
typedef __attribute__((ext_vector_type(16))) int  int16v;

typedef const __attribute__((address_space(1))) void* gas1;
typedef __attribute__((address_space(3))) void* las3;

// ---- ws layout (byte offsets) ----
#define WS_COLMAX   0u          // uint[4096]
#define WS_MASK     16384u      // uchar[4096]
#define WS_IDX      20480u      // int[16]
#define WS_WMAX     32768u      // float[4096]
#define WS_XMAX     49152u      // float[8192]
#define WS_WU       81920u      // float[4096*16]
#define WS_XU       344064u     // float[8192*16]
#define WS_WQ       1048576u    // int8[4096*4096]
#define WS_XQ       34603008u   // int8[8192*4096]

// ---------------- K1: column absmax ----------------
__global__ __launch_bounds__(256) void k_colmax(const float* __restrict__ x,
                                                unsigned int* __restrict__ colmax) {
  int col = blockIdx.x * 256 + threadIdx.x;
  size_t r0 = (size_t)blockIdx.y * 128;
  unsigned int m = 0;
  for (int r = 0; r < 128; ++r) {
    unsigned int b = __float_as_uint(x[(r0 + r) * DIN + col]) & 0x7fffffffu;
    m = b > m ? b : m;
  }
  atomicMax(&colmax[col], m);
}

// ---------------- K2: top-16 columns + mask ----------------
__global__ __launch_bounds__(256) void k_topk(const unsigned int* __restrict__ colmax,
                                              int* __restrict__ idx,
                                              unsigned char* __restrict__ mask) {
  __shared__ unsigned long long keys[DIN];
  __shared__ unsigned long long red[256];
  int t = threadIdx.x;
  for (int i = t; i < DIN; i += 256) {
    keys[i] = (((unsigned long long)colmax[i]) << 12) | (unsigned long long)i;
    mask[i] = 0;
  }
  __syncthreads();
  for (int r = 0; r < KOUT; ++r) {
    unsigned long long m = 0;
    for (int i = t; i < DIN; i += 256) { unsigned long long k = keys[i]; m = k > m ? k : m; }
    red[t] = m;
    __syncthreads();
    for (int s = 128; s > 0; s >>= 1) {
      if (t < s) { unsigned long long o = red[t + s]; if (o > red[t]) red[t] = o; }
      __syncthreads();
    }
    if (t == 0) {
      int bi = (int)(red[0] & 0xFFFu);
      idx[r] = bi;
      mask[bi] = 1;
      keys[bi] = 0;
    }
    __syncthreads();
  }
}

// ---------------- K3: quantize W -> int8 ----------------
__global__ __launch_bounds__(256) void k_quantW(const float* __restrict__ W,
                                                const int* __restrict__ idx,
                                                signed char* __restrict__ Wq,
                                                float* __restrict__ w_max,
                                                float* __restrict__ Wu) {
  __shared__ float row[DIN];
  __shared__ float red[256];
  int o = blockIdx.x, t = threadIdx.x;
  const float* Wr = W + (size_t)o * DIN;
  float m = 0.f;
  for (int i = t * 4; i < DIN; i += 1024) {
    float4 v = *(const float4*)(Wr + i);
    row[i+0] = v.x; row[i+1] = v.y; row[i+2] = v.z; row[i+3] = v.w;
    m = fmaxf(m, fmaxf(fmaxf(fabsf(v.x), fabsf(v.y)), fmaxf(fabsf(v.z), fabsf(v.w))));
  }
  red[t] = m;
  __syncthreads();
  for (int s = 128; s > 0; s >>= 1) {
    if (t < s) red[t] = fmaxf(red[t], red[t + s]);
    __syncthreads();
  }
  float mx = red[0];
  float sc = 127.0f / mx;
  signed char* Wqr = Wq + (size_t)o * DIN;
  for (int i = t * 4; i < DIN; i += 1024) {
    char4 q;
    q.x = (signed char)(int)rintf(row[i+0] * sc);
    q.y = (signed char)(int)rintf(row[i+1] * sc);
    q.z = (signed char)(int)rintf(row[i+2] * sc);
    q.w = (signed char)(int)rintf(row[i+3] * sc);
    *(char4*)(Wqr + i) = q;
  }
  if (t == 0) w_max[o] = mx;
  if (t < KOUT) {
    float wq = rintf(row[idx[t]] * sc);
    Wu[(size_t)o * KOUT + t] = wq * mx / 127.0f;
  }
}

// ---------------- K4: zero outliers + quantize x -> int8 ----------------
__global__ __launch_bounds__(256) void k_quantX(const float* __restrict__ x,
                                                const unsigned char* __restrict__ mask,
                                                const int* __restrict__ idx,
                                                signed char* __restrict__ Xq,
                                                float* __restrict__ x_max,
                                                float* __restrict__ Xu) {
  __shared__ float row[DIN];
  __shared__ float red[256];
  int r = blockIdx.x, t = threadIdx.x;
  const float* xr = x + (size_t)r * DIN;
  float m = 0.f;
  for (int i = t * 4; i < DIN; i += 1024) {
    float4 v = *(const float4*)(xr + i);
    float a0 = mask[i+0] ? 0.f : v.x;
    float a1 = mask[i+1] ? 0.f : v.y;
    float a2 = mask[i+2] ? 0.f : v.z;
    float a3 = mask[i+3] ? 0.f : v.w;
    row[i+0] = a0; row[i+1] = a1; row[i+2] = a2; row[i+3] = a3;
    m = fmaxf(m, fmaxf(fmaxf(fabsf(a0), fabsf(a1)), fmaxf(fabsf(a2), fabsf(a3))));
  }
  red[t] = m;
  __syncthreads();
  for (int s = 128; s > 0; s >>= 1) {
    if (t < s) red[t] = fmaxf(red[t], red[t + s]);
    __syncthreads();
  }
  float mx = red[0];
  float sc = 127.0f / mx;
  signed char* Xqr = Xq + (size_t)r * DIN;
  for (int i = t * 4; i < DIN; i += 1024) {
    char4 q;
    q.x = (signed char)(int)rintf(row[i+0] * sc);
    q.y = (signed char)(int)rintf(row[i+1] * sc);
    q.z = (signed char)(int)rintf(row[i+2] * sc);
    q.w = (signed char)(int)rintf(row[i+3] * sc);
    *(char4*)(Xqr + i) = q;
  }
  if (t == 0) x_max[r] = mx;
  if (t < KOUT) Xu[(size_t)r * KOUT + t] = xr[idx[t]];
}

// ---------------- K5: 128x128 i8 GEMM, 4 waves 64x64, 32x32x32, dbuf, no-unroll kk ----------------
// R17: retry of the 64x64 wave tile (1.0 LDS reads/MFMA vs R15's 1.5) with the
// R16 register-bloat fixed: #pragma unroll 1 on the kk loop keeps only ONE
// iteration's fragments live (16 VGPR) -> acc 64 AGPR + frags 16 + addr ~25
// ~= 105 unified < 128 cap of (256,4). R16's full unroll hoisted 64 frag regs
// -> 176 VGPR -> 1 block/CU -> 395us. LDS dbuf 2x32KB = 64KB -> 2 blocks/CU
// (8 waves). Guards: VGPR <= 128 AND WRITE == 131072KB, else revert to R15.
// Same both-sides swizzle + exact int32 -> bitwise-identical output.
__global__ __launch_bounds__(256, 4) void k_gemm(const signed char* __restrict__ Xq,
                                                 const signed char* __restrict__ Wq,
                                                 const float* __restrict__ x_max,
                                                 const float* __restrict__ w_max,
                                                 const float* __restrict__ Xu,
                                                 const float* __restrict__ Wu,
                                                 const float* __restrict__ bias,
                                                 float* __restrict__ out) {
  __shared__ char smem[65536];
  signed char* sA = (signed char*)smem;             // [2][128][128] i8 (swizzled chunks)
  signed char* sB = sA + 2 * 128 * 128;             // [2][128][128] i8

  int t = threadIdx.x;
  int w = t >> 6, l = t & 63;
  int wr = w >> 1, wc = w & 1;               // wave tile 64x64 at (wr*64, wc*64)
  int l31 = l & 31, lh = l >> 5;             // 32x32 operand: row=l&31, k-half=l>>5
  int sw = l & 7;                            // read-side XOR key (row&7 == l&7)

  // XCD-aware bijective block swizzle: nwg = 64 Mtiles * 32 Ntiles = 2048, %8==0
  int bid = blockIdx.x;
  int wg = (bid & 7) * 256 + (bid >> 3);
  int bM = wg >> 5, bN = wg & 31;

  const signed char* Ab = Xq + (size_t)bM * 128 * DIN;
  const signed char* Bb = Wq + (size_t)bN * 128 * DIN;

  int16v acc[2][2];
  #pragma unroll
  for (int i = 0; i < 2; ++i)
    #pragma unroll
    for (int j = 0; j < 2; ++j)
      acc[i][j] = (int16v){0,0,0,0, 0,0,0,0, 0,0,0,0, 0,0,0,0};

  int srow = w * 32 + (l >> 3);                        // staging row (+ i*8)
  int skel = (((l & 7) ^ ((l >> 3) & 7)) * 16);        // pre-swizzled source chunk (bytes)

#define STAGE(kt_, buf_) do { \
  _Pragma("unroll") \
  for (int i = 0; i < 4; ++i) { \
    int mrow = srow + i * 8; \
    __builtin_amdgcn_global_load_lds((gas1)(Ab + (size_t)mrow * DIN + (kt_) * 128 + skel), \
                                     (las3)(sA + (buf_) * 16384 + (w * 32 + i * 8) * 128), 16, 0, 0); \
    __builtin_amdgcn_global_load_lds((gas1)(Bb + (size_t)mrow * DIN + (kt_) * 128 + skel), \
                                     (las3)(sB + (buf_) * 16384 + (w * 32 + i * 8) * 128), 16, 0, 0); \
  } \
} while (0)

  // prologue: stage tile 0 into buf 0
  STAGE(0, 0);
  __syncthreads();

  for (int kt = 0; kt < NKT; ++kt) {
    int buf = kt & 1;
    if (kt + 1 < NKT) STAGE(kt + 1, buf ^ 1);   // issue next-tile loads BEFORE compute
    const signed char* sAb = sA + buf * 16384;
    const signed char* sBb = sB + buf * 16384;
    #pragma unroll 1
    for (int kk = 0; kk < 4; ++kk) {
      int c = (((kk * 2 + lh) ^ sw) * 16);
      int4v a0 = *(const int4v*)(sAb + (wr * 64 + l31) * 128 + c);
      int4v a1 = *(const int4v*)(sAb + (wr * 64 + 32 + l31) * 128 + c);
      int4v b0 = *(const int4v*)(sBb + (wc * 64 + l31) * 128 + c);
      int4v b1 = *(const int4v*)(sBb + (wc * 64 + 32 + l31) * 128 + c);
      acc[0][0] = __builtin_amdgcn_mfma_i32_32x32x32_i8(a0, b0, acc[0][0], 0, 0, 0);
      acc[0][1] = __builtin_amdgcn_mfma_i32_32x32x32_i8(a0, b1, acc[0][1], 0, 0, 0);
      acc[1][0] = __builtin_amdgcn_mfma_i32_32x32x32_i8(a1, b0, acc[1][0], 0, 0, 0);
      acc[1][1] = __builtin_amdgcn_mfma_i32_32x32x32_i8(a1, b1, acc[1][1], 0, 0, 0);
    }
    __syncthreads();   // drains staging (compiler vmcnt(0)) AFTER compute overlapped it
  }

  // ---- epilogue: stage Xu/Wu/scales/bias tiles into (reused) LDS ----
  float* eXu = (float*)smem;            // [128][17] padded
  float* eWu = eXu + 128 * 17;          // [128][17]
  float* exm = eWu + 128 * 17;          // [128]
  float* ewm = exm + 128;               // [128]
  float* ebs = ewm + 128;               // [128]

  for (int i = t; i < 128 * KOUT; i += 256) {
    int rr = i >> 4, k = i & 15;
    eXu[rr * 17 + k] = Xu[((size_t)(bM * 128 + rr)) * KOUT + k];
    eWu[rr * 17 + k] = Wu[((size_t)(bN * 128 + rr)) * KOUT + k];
  }
  if (t < 128) {
    exm[t] = x_max[bM * 128 + t];
    ewm[t] = w_max[bN * 128 + t];
    ebs[t] = bias[bN * 128 + t];
  }
  __syncthreads();

  #pragma unroll
  for (int ni = 0; ni < 2; ++ni) {
    int cl = wc * 64 + ni * 32 + l31;    // C/D col = lane&31 within quadrant
    float wmc = ewm[cl];
    float bsc = ebs[cl];
    #pragma unroll
    for (int mi = 0; mi < 2; ++mi) {
      #pragma unroll
      for (int reg = 0; reg < 16; ++reg) {
        int rl = wr * 64 + mi * 32 + (reg & 3) + 8 * (reg >> 2) + 4 * lh;
        float xm = exm[rl];
        float rq = (float)acc[mi][ni][reg];
        float v = (float)(_Float16)(rq / 16129.0f) * (xm * wmc);
        float dot = 0.f;
        #pragma unroll
        for (int k = 0; k < KOUT; ++k) dot = fmaf(eXu[rl * 17 + k], eWu[cl * 17 + k], dot);
        out[((size_t)(bM * 128 + rl)) * DOUT + (size_t)bN * 128 + cl] = v + dot + bsc;
      }
    }
  }
}

extern "C" void kernel_launch(void* const* d_in, const int* in_sizes, int n_in,
                              void* d_out, int out_size, void* d_ws, size_t ws_size,
                              hipStream_t stream) {
  const float* x    = (const float*)d_in[0];
  const float* W    = (const float*)d_in[1];
  const float* bias = (const float*)d_in[2];
  float* out = (float*)d_out;
  char* ws = (char*)d_ws;

  unsigned int*   colmax = (unsigned int*)(ws + WS_COLMAX);
  unsigned char*  mask   = (unsigned char*)(ws + WS_MASK);
  int*            idx    = (int*)(ws + WS_IDX);
  float*          w_max  = (float*)(ws + WS_WMAX);
  float*          x_max  = (float*)(ws + WS_XMAX);
  float*          Wu     = (float*)(ws + WS_WU);
  float*          Xu     = (float*)(ws + WS_XU);
  signed char*    Wq     = (signed char*)(ws + WS_WQ);
  signed char*    Xq     = (signed char*)(ws + WS_XQ);

  hipMemsetAsync(colmax, 0, DIN * sizeof(unsigned int), stream);
  k_colmax<<<dim3(DIN / 256, NROWS / 128), 256, 0, stream>>>(x, colmax);
  k_topk<<<1, 256, 0, stream>>>(colmax, idx, mask);
  k_quantW<<<DOUT, 256, 0, stream>>>(W, idx, Wq, w_max, Wu);
  k_quantX<<<NROWS, 256, 0, stream>>>(x, mask, idx, Xq, x_max, Xu);
  k_gemm<<<2048, 256, 0, stream>>>(Xq, Wq, x_max, w_max, Xu, Wu, bias, out);
}

// Round 18
// 334.411 us; speedup vs baseline: 1.2960x; 1.2960x over previous
//
#include <hip/hip_runtime.h>
#include <hip/hip_bf16.h>

#define NROWS 8192
#define DIN   4096
#define DOUT  4096
#define KOUT  16
#define NKT   (DIN / 128)   // 32 K-tiles

typedef __attribute__((ext_vector_type(4)))  int  int4v;
typedef __attribute__((ext_vector_type(16))) int  int16v;

typedef const __attribute__((address_space(1))) void* gas1;
typedef __attribute__((address_space(3))) void* las3;

// ---- ws layout (byte offsets) ----
#define WS_COLMAX   0u          // uint[4096]
#define WS_MASK     16384u      // uchar[4096]
#define WS_IDX      20480u      // int[16]
#define WS_WMAX     32768u      // float[4096]
#define WS_XMAX     49152u      // float[8192]
#define WS_WU       81920u      // float[4096*16]
#define WS_XU       344064u     // float[8192*16]
#define WS_WQ       1048576u    // int8[4096*4096]
#define WS_XQ       34603008u   // int8[8192*4096]

// ---------------- K1: column absmax ----------------
__global__ __launch_bounds__(256) void k_colmax(const float* __restrict__ x,
                                                unsigned int* __restrict__ colmax) {
  int col = blockIdx.x * 256 + threadIdx.x;
  size_t r0 = (size_t)blockIdx.y * 128;
  unsigned int m = 0;
  for (int r = 0; r < 128; ++r) {
    unsigned int b = __float_as_uint(x[(r0 + r) * DIN + col]) & 0x7fffffffu;
    m = b > m ? b : m;
  }
  atomicMax(&colmax[col], m);
}

// ---------------- K2: top-16 columns + mask ----------------
__global__ __launch_bounds__(256) void k_topk(const unsigned int* __restrict__ colmax,
                                              int* __restrict__ idx,
                                              unsigned char* __restrict__ mask) {
  __shared__ unsigned long long keys[DIN];
  __shared__ unsigned long long red[256];
  int t = threadIdx.x;
  for (int i = t; i < DIN; i += 256) {
    keys[i] = (((unsigned long long)colmax[i]) << 12) | (unsigned long long)i;
    mask[i] = 0;
  }
  __syncthreads();
  for (int r = 0; r < KOUT; ++r) {
    unsigned long long m = 0;
    for (int i = t; i < DIN; i += 256) { unsigned long long k = keys[i]; m = k > m ? k : m; }
    red[t] = m;
    __syncthreads();
    for (int s = 128; s > 0; s >>= 1) {
      if (t < s) { unsigned long long o = red[t + s]; if (o > red[t]) red[t] = o; }
      __syncthreads();
    }
    if (t == 0) {
      int bi = (int)(red[0] & 0xFFFu);
      idx[r] = bi;
      mask[bi] = 1;
      keys[bi] = 0;
    }
    __syncthreads();
  }
}

// ---------------- K3: quantize W -> int8 ----------------
__global__ __launch_bounds__(256) void k_quantW(const float* __restrict__ W,
                                                const int* __restrict__ idx,
                                                signed char* __restrict__ Wq,
                                                float* __restrict__ w_max,
                                                float* __restrict__ Wu) {
  __shared__ float row[DIN];
  __shared__ float red[256];
  int o = blockIdx.x, t = threadIdx.x;
  const float* Wr = W + (size_t)o * DIN;
  float m = 0.f;
  for (int i = t * 4; i < DIN; i += 1024) {
    float4 v = *(const float4*)(Wr + i);
    row[i+0] = v.x; row[i+1] = v.y; row[i+2] = v.z; row[i+3] = v.w;
    m = fmaxf(m, fmaxf(fmaxf(fabsf(v.x), fabsf(v.y)), fmaxf(fabsf(v.z), fabsf(v.w))));
  }
  red[t] = m;
  __syncthreads();
  for (int s = 128; s > 0; s >>= 1) {
    if (t < s) red[t] = fmaxf(red[t], red[t + s]);
    __syncthreads();
  }
  float mx = red[0];
  float sc = 127.0f / mx;
  signed char* Wqr = Wq + (size_t)o * DIN;
  for (int i = t * 4; i < DIN; i += 1024) {
    char4 q;
    q.x = (signed char)(int)rintf(row[i+0] * sc);
    q.y = (signed char)(int)rintf(row[i+1] * sc);
    q.z = (signed char)(int)rintf(row[i+2] * sc);
    q.w = (signed char)(int)rintf(row[i+3] * sc);
    *(char4*)(Wqr + i) = q;
  }
  if (t == 0) w_max[o] = mx;
  if (t < KOUT) {
    float wq = rintf(row[idx[t]] * sc);
    Wu[(size_t)o * KOUT + t] = wq * mx / 127.0f;
  }
}

// ---------------- K4: zero outliers + quantize x -> int8 ----------------
__global__ __launch_bounds__(256) void k_quantX(const float* __restrict__ x,
                                                const unsigned char* __restrict__ mask,
                                                const int* __restrict__ idx,
                                                signed char* __restrict__ Xq,
                                                float* __restrict__ x_max,
                                                float* __restrict__ Xu) {
  __shared__ float row[DIN];
  __shared__ float red[256];
  int r = blockIdx.x, t = threadIdx.x;
  const float* xr = x + (size_t)r * DIN;
  float m = 0.f;
  for (int i = t * 4; i < DIN; i += 1024) {
    float4 v = *(const float4*)(xr + i);
    float a0 = mask[i+0] ? 0.f : v.x;
    float a1 = mask[i+1] ? 0.f : v.y;
    float a2 = mask[i+2] ? 0.f : v.z;
    float a3 = mask[i+3] ? 0.f : v.w;
    row[i+0] = a0; row[i+1] = a1; row[i+2] = a2; row[i+3] = a3;
    m = fmaxf(m, fmaxf(fmaxf(fabsf(a0), fabsf(a1)), fmaxf(fabsf(a2), fabsf(a3))));
  }
  red[t] = m;
  __syncthreads();
  for (int s = 128; s > 0; s >>= 1) {
    if (t < s) red[t] = fmaxf(red[t], red[t + s]);
    __syncthreads();
  }
  float mx = red[0];
  float sc = 127.0f / mx;
  signed char* Xqr = Xq + (size_t)r * DIN;
  for (int i = t * 4; i < DIN; i += 1024) {
    char4 q;
    q.x = (signed char)(int)rintf(row[i+0] * sc);
    q.y = (signed char)(int)rintf(row[i+1] * sc);
    q.z = (signed char)(int)rintf(row[i+2] * sc);
    q.w = (signed char)(int)rintf(row[i+3] * sc);
    *(char4*)(Xqr + i) = q;
  }
  if (t == 0) x_max[r] = mx;
  if (t < KOUT) Xu[(size_t)r * KOUT + t] = xr[idx[t]];
}

// ---------------- K5: 128x128 i8 GEMM, 8 waves 64x32, A-dbuf + B-single (48KB) ----------------
// R18 = R15 hot loop (best zero-spill: 60 VGPR, 253us) with LDS cut 64->48KB so
// THREE blocks co-reside per CU (144KB LDS, 24 waves) instead of two:
//   A double-buffered (2x16KB): STAGE_A(kt+1) issued before compute, overlaps it.
//   B single-buffered (16KB):   STAGE_B(kt+1) between two barriers after compute
//                               (WAR-safe; its latency is hidden by the other
//                               two resident blocks' compute).
// 64x64-wave-tile family is dead (R14/R16/R17: compiler spills or 176 VGPR).
// Guards: VGPR==60, WRITE==131072KB, LDS_Block_Size==49152.
// Same both-sides swizzle + exact int32 accumulation -> bitwise-identical output.
__global__ __launch_bounds__(512, 4) void k_gemm(const signed char* __restrict__ Xq,
                                                 const signed char* __restrict__ Wq,
                                                 const float* __restrict__ x_max,
                                                 const float* __restrict__ w_max,
                                                 const float* __restrict__ Xu,
                                                 const float* __restrict__ Wu,
                                                 const float* __restrict__ bias,
                                                 float* __restrict__ out) {
  __shared__ char smem[49152];
  signed char* sA = (signed char*)smem;             // [2][128][128] i8 (swizzled chunks)
  signed char* sB = sA + 2 * 128 * 128;             // [128][128] i8 (single buffer)

  int t = threadIdx.x;
  int wid = t >> 6, l = t & 63;
  int wr = wid >> 2, wc = wid & 3;           // wave tile 64x32 at (wr*64, wc*32)
  int l31 = l & 31, lh = l >> 5;             // 32x32 operand: row=l&31, k-half=l>>5
  int sw = l & 7;                            // read-side XOR key (row&7 == l&7)

  // XCD-aware bijective block swizzle: nwg = 64 Mtiles * 32 Ntiles = 2048, %8==0
  int bid = blockIdx.x;
  int wg = (bid & 7) * 256 + (bid >> 3);
  int bM = wg >> 5, bN = wg & 31;

  const signed char* Ab = Xq + (size_t)bM * 128 * DIN;
  const signed char* Bb = Wq + (size_t)bN * 128 * DIN;

  int16v acc[2];
  #pragma unroll
  for (int i = 0; i < 2; ++i)
    acc[i] = (int16v){0,0,0,0, 0,0,0,0, 0,0,0,0, 0,0,0,0};

  int srow = wid * 16 + (l >> 3);                      // staging row (+ i*8)
  int skel = (((l & 7) ^ ((l >> 3) & 7)) * 16);        // pre-swizzled source chunk (bytes)

#define STAGE_A(kt_, buf_) do { \
  _Pragma("unroll") \
  for (int i = 0; i < 2; ++i) { \
    int mrow = srow + i * 8; \
    __builtin_amdgcn_global_load_lds((gas1)(Ab + (size_t)mrow * DIN + (kt_) * 128 + skel), \
                                     (las3)(sA + (buf_) * 16384 + (wid * 16 + i * 8) * 128), 16, 0, 0); \
  } \
} while (0)
#define STAGE_B(kt_) do { \
  _Pragma("unroll") \
  for (int i = 0; i < 2; ++i) { \
    int mrow = srow + i * 8; \
    __builtin_amdgcn_global_load_lds((gas1)(Bb + (size_t)mrow * DIN + (kt_) * 128 + skel), \
                                     (las3)(sB + (wid * 16 + i * 8) * 128), 16, 0, 0); \
  } \
} while (0)

  // prologue: stage tile 0 (A into buf0, B into the single buffer)
  STAGE_A(0, 0);
  STAGE_B(0);
  __syncthreads();

  for (int kt = 0; kt < NKT; ++kt) {
    int buf = kt & 1;
    if (kt + 1 < NKT) STAGE_A(kt + 1, buf ^ 1);   // A prefetch overlaps compute
    const signed char* sAb = sA + buf * 16384;
    #pragma unroll
    for (int kk = 0; kk < 4; ++kk) {
      int c = (((kk * 2 + lh) ^ sw) * 16);
      int4v a0 = *(const int4v*)(sAb + (wr * 64 + l31) * 128 + c);
      int4v a1 = *(const int4v*)(sAb + (wr * 64 + 32 + l31) * 128 + c);
      int4v b0 = *(const int4v*)(sB + (wc * 32 + l31) * 128 + c);
      acc[0] = __builtin_amdgcn_mfma_i32_32x32x32_i8(a0, b0, acc[0], 0, 0, 0);
      acc[1] = __builtin_amdgcn_mfma_i32_32x32x32_i8(a1, b0, acc[1], 0, 0, 0);
    }
    __syncthreads();                              // all waves done reading B(kt)
    if (kt + 1 < NKT) {
      STAGE_B(kt + 1);                            // restage single B buffer
      __syncthreads();                            // B(kt+1) visible for next iter
    }
  }

  // ---- epilogue: stage Xu/Wu/scales/bias tiles into (reused) LDS ----
  float* eXu = (float*)smem;            // [128][17] padded
  float* eWu = eXu + 128 * 17;          // [128][17]
  float* exm = eWu + 128 * 17;          // [128]
  float* ewm = exm + 128;               // [128]
  float* ebs = ewm + 128;               // [128]

  __syncthreads();
  for (int i = t; i < 128 * KOUT; i += 512) {
    int rr = i >> 4, k = i & 15;
    eXu[rr * 17 + k] = Xu[((size_t)(bM * 128 + rr)) * KOUT + k];
    eWu[rr * 17 + k] = Wu[((size_t)(bN * 128 + rr)) * KOUT + k];
  }
  if (t < 128) {
    exm[t] = x_max[bM * 128 + t];
    ewm[t] = w_max[bN * 128 + t];
    ebs[t] = bias[bN * 128 + t];
  }
  __syncthreads();

  int cl = wc * 32 + l31;                // C/D col = lane&31
  float wmc = ewm[cl];
  float bsc = ebs[cl];
  #pragma unroll
  for (int mi = 0; mi < 2; ++mi) {
    #pragma unroll
    for (int reg = 0; reg < 16; ++reg) {
      int rl = wr * 64 + mi * 32 + (reg & 3) + 8 * (reg >> 2) + 4 * lh;
      float xm = exm[rl];
      float rq = (float)acc[mi][reg];
      float v = (float)(_Float16)(rq / 16129.0f) * (xm * wmc);
      float dot = 0.f;
      #pragma unroll
      for (int k = 0; k < KOUT; ++k) dot = fmaf(eXu[rl * 17 + k], eWu[cl * 17 + k], dot);
      out[((size_t)(bM * 128 + rl)) * DOUT + (size_t)bN * 128 + cl] = v + dot + bsc;
    }
  }
}

extern "C" void kernel_launch(void* const* d_in, const int* in_sizes, int n_in,
                              void* d_out, int out_size, void* d_ws, size_t ws_size,
                              hipStream_t stream) {
  const float* x    = (const float*)d_in[0];
  const float* W    = (const float*)d_in[1];
  const float* bias = (const float*)d_in[2];
  float* out = (float*)d_out;
  char* ws = (char*)d_ws;

  unsigned int*   colmax = (unsigned int*)(ws + WS_COLMAX);
  unsigned char*  mask   = (unsigned char*)(ws + WS_MASK);
  int*            idx    = (int*)(ws + WS_IDX);
  float*          w_max  = (float*)(ws + WS_WMAX);
  float*          x_max  = (float*)(ws + WS_XMAX);
  float*          Wu     = (float*)(ws + WS_WU);
  float*          Xu     = (float*)(ws + WS_XU);
  signed char*    Wq     = (signed char*)(ws + WS_WQ);
  signed char*    Xq     = (signed char*)(ws + WS_XQ);

  hipMemsetAsync(colmax, 0, DIN * sizeof(unsigned int), stream);
  k_colmax<<<dim3(DIN / 256, NROWS / 128), 256, 0, stream>>>(x, colmax);
  k_topk<<<1, 256, 0, stream>>>(colmax, idx, mask);
  k_quantW<<<DOUT, 256, 0, stream>>>(W, idx, Wq, w_max, Wu);
  k_quantX<<<NROWS, 256, 0, stream>>>(x, mask, idx, Xq, x_max, Xu);
  k_gemm<<<2048, 512, 0, stream>>>(Xq, Wq, x_max, w_max, Xu, Wu, bias, out);
}

// Round 19
// 331.142 us; speedup vs baseline: 1.3088x; 1.0099x over previous
//
#include <hip/hip_runtime.h>
#include <hip/hip_bf16.h>

#define NROWS 8192
#define DIN   4096
#define DOUT  4096
#define KOUT  16
#define NKT   (DIN / 128)   // 32 K-tiles

typedef __attribute__((ext_vector_type(4)))  int  int4v;
typedef __attribute__((ext_vector_type(16))) int  int16v;

typedef const __attribute__((address_space(1))) void* gas1;
typedef __attribute__((address_space(3))) void* las3;

// ---- ws layout (byte offsets) ----
#define WS_COLMAX   0u          // uint[4096]
#define WS_MASK     16384u      // uchar[4096]
#define WS_IDX      20480u      // int[16]
#define WS_WMAX     32768u      // float[4096]
#define WS_XMAX     49152u      // float[8192]
#define WS_WU       81920u      // float[4096*16]
#define WS_XU       344064u     // float[8192*16]
#define WS_WQ       1048576u    // int8[4096*4096]
#define WS_XQ       34603008u   // int8[8192*4096]

// ---------------- K1: column absmax ----------------
__global__ __launch_bounds__(256) void k_colmax(const float* __restrict__ x,
                                                unsigned int* __restrict__ colmax) {
  int col = blockIdx.x * 256 + threadIdx.x;
  size_t r0 = (size_t)blockIdx.y * 128;
  unsigned int m = 0;
  for (int r = 0; r < 128; ++r) {
    unsigned int b = __float_as_uint(x[(r0 + r) * DIN + col]) & 0x7fffffffu;
    m = b > m ? b : m;
  }
  atomicMax(&colmax[col], m);
}

// ---------------- K2: top-16 columns + mask ----------------
__global__ __launch_bounds__(256) void k_topk(const unsigned int* __restrict__ colmax,
                                              int* __restrict__ idx,
                                              unsigned char* __restrict__ mask) {
  __shared__ unsigned long long keys[DIN];
  __shared__ unsigned long long red[256];
  int t = threadIdx.x;
  for (int i = t; i < DIN; i += 256) {
    keys[i] = (((unsigned long long)colmax[i]) << 12) | (unsigned long long)i;
    mask[i] = 0;
  }
  __syncthreads();
  for (int r = 0; r < KOUT; ++r) {
    unsigned long long m = 0;
    for (int i = t; i < DIN; i += 256) { unsigned long long k = keys[i]; m = k > m ? k : m; }
    red[t] = m;
    __syncthreads();
    for (int s = 128; s > 0; s >>= 1) {
      if (t < s) { unsigned long long o = red[t + s]; if (o > red[t]) red[t] = o; }
      __syncthreads();
    }
    if (t == 0) {
      int bi = (int)(red[0] & 0xFFFu);
      idx[r] = bi;
      mask[bi] = 1;
      keys[bi] = 0;
    }
    __syncthreads();
  }
}

// ---------------- K3: quantize W -> int8 ----------------
__global__ __launch_bounds__(256) void k_quantW(const float* __restrict__ W,
                                                const int* __restrict__ idx,
                                                signed char* __restrict__ Wq,
                                                float* __restrict__ w_max,
                                                float* __restrict__ Wu) {
  __shared__ float row[DIN];
  __shared__ float red[256];
  int o = blockIdx.x, t = threadIdx.x;
  const float* Wr = W + (size_t)o * DIN;
  float m = 0.f;
  for (int i = t * 4; i < DIN; i += 1024) {
    float4 v = *(const float4*)(Wr + i);
    row[i+0] = v.x; row[i+1] = v.y; row[i+2] = v.z; row[i+3] = v.w;
    m = fmaxf(m, fmaxf(fmaxf(fabsf(v.x), fabsf(v.y)), fmaxf(fabsf(v.z), fabsf(v.w))));
  }
  red[t] = m;
  __syncthreads();
  for (int s = 128; s > 0; s >>= 1) {
    if (t < s) red[t] = fmaxf(red[t], red[t + s]);
    __syncthreads();
  }
  float mx = red[0];
  float sc = 127.0f / mx;
  signed char* Wqr = Wq + (size_t)o * DIN;
  for (int i = t * 4; i < DIN; i += 1024) {
    char4 q;
    q.x = (signed char)(int)rintf(row[i+0] * sc);
    q.y = (signed char)(int)rintf(row[i+1] * sc);
    q.z = (signed char)(int)rintf(row[i+2] * sc);
    q.w = (signed char)(int)rintf(row[i+3] * sc);
    *(char4*)(Wqr + i) = q;
  }
  if (t == 0) w_max[o] = mx;
  if (t < KOUT) {
    float wq = rintf(row[idx[t]] * sc);
    Wu[(size_t)o * KOUT + t] = wq * mx / 127.0f;
  }
}

// ---------------- K4: zero outliers + quantize x -> int8 ----------------
__global__ __launch_bounds__(256) void k_quantX(const float* __restrict__ x,
                                                const unsigned char* __restrict__ mask,
                                                const int* __restrict__ idx,
                                                signed char* __restrict__ Xq,
                                                float* __restrict__ x_max,
                                                float* __restrict__ Xu) {
  __shared__ float row[DIN];
  __shared__ float red[256];
  int r = blockIdx.x, t = threadIdx.x;
  const float* xr = x + (size_t)r * DIN;
  float m = 0.f;
  for (int i = t * 4; i < DIN; i += 1024) {
    float4 v = *(const float4*)(xr + i);
    float a0 = mask[i+0] ? 0.f : v.x;
    float a1 = mask[i+1] ? 0.f : v.y;
    float a2 = mask[i+2] ? 0.f : v.z;
    float a3 = mask[i+3] ? 0.f : v.w;
    row[i+0] = a0; row[i+1] = a1; row[i+2] = a2; row[i+3] = a3;
    m = fmaxf(m, fmaxf(fmaxf(fabsf(a0), fabsf(a1)), fmaxf(fabsf(a2), fabsf(a3))));
  }
  red[t] = m;
  __syncthreads();
  for (int s = 128; s > 0; s >>= 1) {
    if (t < s) red[t] = fmaxf(red[t], red[t + s]);
    __syncthreads();
  }
  float mx = red[0];
  float sc = 127.0f / mx;
  signed char* Xqr = Xq + (size_t)r * DIN;
  for (int i = t * 4; i < DIN; i += 1024) {
    char4 q;
    q.x = (signed char)(int)rintf(row[i+0] * sc);
    q.y = (signed char)(int)rintf(row[i+1] * sc);
    q.z = (signed char)(int)rintf(row[i+2] * sc);
    q.w = (signed char)(int)rintf(row[i+3] * sc);
    *(char4*)(Xqr + i) = q;
  }
  if (t == 0) x_max[r] = mx;
  if (t < KOUT) Xu[(size_t)r * KOUT + t] = xr[idx[t]];
}

// ---------------- K5: 128x128 i8 GEMM, 8 waves 64x32, 32x32x32, double-buffered ----------------
// R19 = R15 restored verbatim (session-best: k_gemm 250-256us, total 332us,
// 60 VGPR, zero spill, exact int32 accumulation).
// Session findings baked in:
//  - i8 32x32x32 core: exact int32 accum, smallest live set (92 unified regs).
//  - 8 waves of 64x32: only wave-tile shape that is spill-free on this compiler
//    (64x64 family: R14/R16/R17 all spill or hoist to 160-176 VGPR).
//  - LDS double-buffer with STAGE-before-compute: overlaps global->LDS latency
//    with compute; the compiler's vmcnt(0) drain at the barrier is then harmless.
//  - Both-sides XOR swizzle (chunk ^ row&7) on staging source + LDS read.
//  - XCD-aware bijective block swizzle for L2 locality.
// Measured plateau: MfmaUtil 23.5% == MFMA cycle content; remainder is the
// LDS-pipe + barrier-synchronized latency floor of the 2-barrier structure.
__global__ __launch_bounds__(512, 4) void k_gemm(const signed char* __restrict__ Xq,
                                                 const signed char* __restrict__ Wq,
                                                 const float* __restrict__ x_max,
                                                 const float* __restrict__ w_max,
                                                 const float* __restrict__ Xu,
                                                 const float* __restrict__ Wu,
                                                 const float* __restrict__ bias,
                                                 float* __restrict__ out) {
  __shared__ char smem[65536];
  signed char* sA = (signed char*)smem;             // [2][128][128] i8 (swizzled chunks)
  signed char* sB = sA + 2 * 128 * 128;             // [2][128][128] i8

  int t = threadIdx.x;
  int wid = t >> 6, l = t & 63;
  int wr = wid >> 2, wc = wid & 3;           // wave tile 64x32 at (wr*64, wc*32)
  int l31 = l & 31, lh = l >> 5;             // 32x32 operand: row=l&31, k-half=l>>5
  int sw = l & 7;                            // read-side XOR key (row&7 == l&7)

  // XCD-aware bijective block swizzle: nwg = 64 Mtiles * 32 Ntiles = 2048, %8==0
  int bid = blockIdx.x;
  int wg = (bid & 7) * 256 + (bid >> 3);
  int bM = wg >> 5, bN = wg & 31;

  const signed char* Ab = Xq + (size_t)bM * 128 * DIN;
  const signed char* Bb = Wq + (size_t)bN * 128 * DIN;

  int16v acc[2];
  #pragma unroll
  for (int i = 0; i < 2; ++i)
    acc[i] = (int16v){0,0,0,0, 0,0,0,0, 0,0,0,0, 0,0,0,0};

  int srow = wid * 16 + (l >> 3);                      // staging row (+ i*8)
  int skel = (((l & 7) ^ ((l >> 3) & 7)) * 16);        // pre-swizzled source chunk (bytes)

#define STAGE(kt_, buf_) do { \
  _Pragma("unroll") \
  for (int i = 0; i < 2; ++i) { \
    int mrow = srow + i * 8; \
    __builtin_amdgcn_global_load_lds((gas1)(Ab + (size_t)mrow * DIN + (kt_) * 128 + skel), \
                                     (las3)(sA + (buf_) * 16384 + (wid * 16 + i * 8) * 128), 16, 0, 0); \
    __builtin_amdgcn_global_load_lds((gas1)(Bb + (size_t)mrow * DIN + (kt_) * 128 + skel), \
                                     (las3)(sB + (buf_) * 16384 + (wid * 16 + i * 8) * 128), 16, 0, 0); \
  } \
} while (0)

  // prologue: stage tile 0 into buf 0
  STAGE(0, 0);
  __syncthreads();

  for (int kt = 0; kt < NKT; ++kt) {
    int buf = kt & 1;
    if (kt + 1 < NKT) STAGE(kt + 1, buf ^ 1);   // issue next-tile loads BEFORE compute
    const signed char* sAb = sA + buf * 16384;
    const signed char* sBb = sB + buf * 16384;
    #pragma unroll
    for (int kk = 0; kk < 4; ++kk) {
      int c = (((kk * 2 + lh) ^ sw) * 16);
      int4v a0 = *(const int4v*)(sAb + (wr * 64 + l31) * 128 + c);
      int4v a1 = *(const int4v*)(sAb + (wr * 64 + 32 + l31) * 128 + c);
      int4v b0 = *(const int4v*)(sBb + (wc * 32 + l31) * 128 + c);
      acc[0] = __builtin_amdgcn_mfma_i32_32x32x32_i8(a0, b0, acc[0], 0, 0, 0);
      acc[1] = __builtin_amdgcn_mfma_i32_32x32x32_i8(a1, b0, acc[1], 0, 0, 0);
    }
    __syncthreads();   // drains staging (compiler vmcnt(0)) AFTER compute overlapped it
  }

  // ---- epilogue: stage Xu/Wu/scales/bias tiles into (reused) LDS ----
  float* eXu = (float*)smem;            // [128][17] padded
  float* eWu = eXu + 128 * 17;          // [128][17]
  float* exm = eWu + 128 * 17;          // [128]
  float* ewm = exm + 128;               // [128]
  float* ebs = ewm + 128;               // [128]

  for (int i = t; i < 128 * KOUT; i += 512) {
    int rr = i >> 4, k = i & 15;
    eXu[rr * 17 + k] = Xu[((size_t)(bM * 128 + rr)) * KOUT + k];
    eWu[rr * 17 + k] = Wu[((size_t)(bN * 128 + rr)) * KOUT + k];
  }
  if (t < 128) {
    exm[t] = x_max[bM * 128 + t];
    ewm[t] = w_max[bN * 128 + t];
    ebs[t] = bias[bN * 128 + t];
  }
  __syncthreads();

  int cl = wc * 32 + l31;                // C/D col = lane&31
  float wmc = ewm[cl];
  float bsc = ebs[cl];
  #pragma unroll
  for (int mi = 0; mi < 2; ++mi) {
    #pragma unroll
    for (int reg = 0; reg < 16; ++reg) {
      int rl = wr * 64 + mi * 32 + (reg & 3) + 8 * (reg >> 2) + 4 * lh;
      float xm = exm[rl];
      float rq = (float)acc[mi][reg];
      float v = (float)(_Float16)(rq / 16129.0f) * (xm * wmc);
      float dot = 0.f;
      #pragma unroll
      for (int k = 0; k < KOUT; ++k) dot = fmaf(eXu[rl * 17 + k], eWu[cl * 17 + k], dot);
      out[((size_t)(bM * 128 + rl)) * DOUT + (size_t)bN * 128 + cl] = v + dot + bsc;
    }
  }
}

extern "C" void kernel_launch(void* const* d_in, const int* in_sizes, int n_in,
                              void* d_out, int out_size, void* d_ws, size_t ws_size,
                              hipStream_t stream) {
  const float* x    = (const float*)d_in[0];
  const float* W    = (const float*)d_in[1];
  const float* bias = (const float*)d_in[2];
  float* out = (float*)d_out;
  char* ws = (char*)d_ws;

  unsigned int*   colmax = (unsigned int*)(ws + WS_COLMAX);
  unsigned char*  mask   = (unsigned char*)(ws + WS_MASK);
  int*            idx    = (int*)(ws + WS_IDX);
  float*          w_max  = (float*)(ws + WS_WMAX);
  float*          x_max  = (float*)(ws + WS_XMAX);
  float*          Wu     = (float*)(ws + WS_WU);
  float*          Xu     = (float*)(ws + WS_XU);
  signed char*    Wq     = (signed char*)(ws + WS_WQ);
  signed char*    Xq     = (signed char*)(ws + WS_XQ);

  hipMemsetAsync(colmax, 0, DIN * sizeof(unsigned int), stream);
  k_colmax<<<dim3(DIN / 256, NROWS / 128), 256, 0, stream>>>(x, colmax);
  k_topk<<<1, 256, 0, stream>>>(colmax, idx, mask);
  k_quantW<<<DOUT, 256, 0, stream>>>(W, idx, Wq, w_max, Wu);
  k_quantX<<<NROWS, 256, 0, stream>>>(x, mask, idx, Xq, x_max, Xu);
  k_gemm<<<2048, 512, 0, stream>>>(Xq, Wq, x_max, w_max, Xu, Wu, bias, out);
}